// Round 6
// baseline (409.415 us; speedup 1.0000x reference)
//
#include <hip/hip_runtime.h>
#include <hip/hip_bf16.h>

// RGCN layer, MI355X — round 17.
// r16 post-mortem: sequential t_buf writes moved the 164MB permutation cost
// to the read side — reduce now top at 81.6us, 1.75TB/s random 256B gathers.
// FIX: two-level sort key (dst>>7)*65+etype (10205 buckets, mean 62.7 edges).
// Conv tiles = per-bucket (one rel each, independent blocks, sequential
// writes); a dst's edges now lie in a 1.05MB L2-resident window -> reduce
// gather becomes L2-local. Conv: 64-row x 128-col tiles, 16-row waves,
// LDS 49KB -> 3 blocks/CU. Reduce: 626 blocks x 32 dsts, body unchanged.
// Permuted col layout / resid / bn inherited from r16 verbatim.

#define N_NODES 20000
#define E_EDGES 640000
#define R_REL   65
#define NGRP_B  157                 // ceil(20000/128)
#define NKEY_B  (NGRP_B * R_REL)    // 10205
#define NB_RESID 313
#define MAX_TILES 20480             // >= 10205 + E/64 = 20205
#define TM      64

typedef __attribute__((ext_vector_type(8))) short bf16x8;
typedef __attribute__((ext_vector_type(4))) float f32x4;
typedef __attribute__((ext_vector_type(4))) unsigned int u32x4;
typedef __attribute__((ext_vector_type(2))) unsigned int u32x2;

__device__ __forceinline__ unsigned short f2bf(float x) {
    union { float f; unsigned int u; } c; c.f = x;
    unsigned int b = c.u + 0x7fffu + ((c.u >> 16) & 1u);   // RTNE
    return (unsigned short)(b >> 16);
}
__device__ __forceinline__ float bf2f_lo(unsigned int u) {
    union { unsigned int u; float f; } c; c.u = u << 16; return c.f;
}
__device__ __forceinline__ float bf2f_hi(unsigned int u) {
    union { unsigned int u; float f; } c; c.u = u & 0xffff0000u; return c.f;
}
__device__ __forceinline__ void async16(const void* g, void* l) {
    __builtin_amdgcn_global_load_lds(
        (const __attribute__((address_space(1))) unsigned int*)g,
        (__attribute__((address_space(3))) unsigned int*)l, 16, 0, 0);
}
__device__ __forceinline__ int unperm(int p) {      // permuted pos -> true col
    return (p & 64) + ((p & 3) << 4) + ((p >> 2) & 15);
}

// ---------------- K1: basis GEMM || bucket+dst hist || f32->bf16 cvt -------
__global__ void k_prep1(const float* __restrict__ comp, const float* __restrict__ basis,
                        float* __restrict__ W32, const int* __restrict__ et,
                        const int* __restrict__ dstA, int* __restrict__ gh3,
                        int* __restrict__ gh2, const float* __restrict__ node_feats,
                        unsigned short* __restrict__ node_bf) {
    __shared__ float lc[16 * 65];
    int b = blockIdx.x, t = threadIdx.x;
    if (b < 320) {                                  // basis GEMM
        int r0 = (b >> 6) * 16;
        int col = (b & 63) * 256 + t;
        for (int j = t; j < 16 * 65; j += 256) {
            int rr = r0 + j / 65;
            lc[j] = (rr < R_REL) ? comp[rr * 65 + (j % 65)] : 0.f;
        }
        __syncthreads();
        float acc[16];
#pragma unroll
        for (int j = 0; j < 16; ++j) acc[j] = 0.f;
        for (int k = 0; k < 65; ++k) {
            float v = basis[k * 16384 + col];
#pragma unroll
            for (int j = 0; j < 16; ++j) acc[j] += lc[j * 65 + k] * v;
        }
#pragma unroll
        for (int j = 0; j < 16; ++j) {
            int rr = r0 + j;
            if (rr < R_REL) W32[rr * 16384 + col] = acc[j];
        }
    } else if (b < 832) {                           // histograms
        for (int i = (b - 320) * 256 + t; i < E_EDGES; i += 512 * 256) {
            int d = dstA[i];
            atomicAdd(&gh3[(d >> 7) * 65 + et[i]], 1);
            atomicAdd(&gh2[d], 1);
        }
    } else {                                        // cvt fp32 -> bf16 (x4)
        int i = (b - 832) * 256 + t;
        if (i < N_NODES * 32) {
            float4 v = reinterpret_cast<const float4*>(node_feats)[i];
            __hip_bfloat162 b0 = __float22bfloat162_rn(make_float2(v.x, v.y));
            __hip_bfloat162 b1 = __float22bfloat162_rn(make_float2(v.z, v.w));
            u32x2 pk;
            pk.x = *reinterpret_cast<unsigned int*>(&b0);
            pk.y = *reinterpret_cast<unsigned int*>(&b1);
            reinterpret_cast<u32x2*>(node_bf)[i] = pk;
        }
    }
}

// ---------------- K2: bucket scan || dst scan || W transposes --------------
__global__ void k_prep3(const int* __restrict__ gh3, int* __restrict__ segB,
                        int* __restrict__ cnt3, const int* __restrict__ gh2,
                        int* __restrict__ cnt2, int* __restrict__ seg,
                        const float* __restrict__ W32, unsigned short* __restrict__ Wt,
                        const float* __restrict__ Wresf, unsigned short* __restrict__ Wrest) {
    int b = blockIdx.x, t = threadIdx.x;
    if (b < 40) {                                   // scan 10205 buckets
        __shared__ int red[256];
        __shared__ int pref;
        int acc = 0;
        for (int i = t; i < b * 256; i += 256) acc += gh3[i];
        red[t] = acc;
        __syncthreads();
        for (int off = 128; off > 0; off >>= 1) {
            if (t < off) red[t] += red[t + off];
            __syncthreads();
        }
        if (t == 0) pref = red[0];
        __syncthreads();
        int i = b * 256 + t;
        int v = (i < NKEY_B) ? gh3[i] : 0;
        red[t] = v;
        __syncthreads();
        for (int off = 1; off < 256; off <<= 1) {
            int x = (t >= off) ? red[t - off] : 0;
            __syncthreads();
            red[t] += x;
            __syncthreads();
        }
        int excl = red[t] - v + pref;
        if (i < NKEY_B) {
            segB[i] = excl;
            cnt3[i] = excl;
            if (i == NKEY_B - 1) segB[NKEY_B] = excl + v;
        }
    } else if (b < 120) {                           // scan 20000 dsts
        __shared__ int red[256];
        __shared__ int pref;
        int b2 = b - 40;
        int acc = 0;
        for (int i = t; i < b2 * 256; i += 256) acc += gh2[i];
        red[t] = acc;
        __syncthreads();
        for (int off = 128; off > 0; off >>= 1) {
            if (t < off) red[t] += red[t + off];
            __syncthreads();
        }
        if (t == 0) pref = red[0];
        __syncthreads();
        int i = b2 * 256 + t;
        int v = (i < N_NODES) ? gh2[i] : 0;
        red[t] = v;
        __syncthreads();
        for (int off = 1; off < 256; off <<= 1) {
            int x = (t >= off) ? red[t - off] : 0;
            __syncthreads();
            red[t] += x;
            __syncthreads();
        }
        int excl = red[t] - v + pref;
        if (i < N_NODES) {
            cnt2[i] = excl;
            seg[i] = excl;
            if (i == N_NODES - 1) seg[N_NODES] = excl + v;
        }
    } else {                                        // transposes (264 blocks)
        __shared__ float tile[64][65];
        int bb = b - 120;
        const float* s; unsigned short* d; int sub;
        if (bb < R_REL * 4) { s = W32 + (size_t)(bb >> 2) * 16384; d = Wt + (size_t)(bb >> 2) * 16384; sub = bb & 3; }
        else { s = Wresf; d = Wrest; sub = bb - R_REL * 4; }
        int ot = (sub >> 1) & 1, itl = sub & 1;
        int tx = t & 63, ty = t >> 6;
        for (int it = 0; it < 16; ++it) {
            int i = ty + it * 4;
            tile[i][tx] = s[(itl * 64 + i) * 128 + ot * 64 + tx];
        }
        __syncthreads();
        for (int it = 0; it < 16; ++it) {
            int o = ty + it * 4;
            d[(ot * 64 + o) * 128 + itl * 64 + tx] = f2bf(tile[tx][o]);
        }
    }
}

// ---------------- K3: bucket scatter + eidx + tile emission ----------------
__global__ void k_scatter2(const int* __restrict__ et, const int* __restrict__ srcA,
                           const int* __restrict__ dstA, const float* __restrict__ norm,
                           int* __restrict__ cnt3, int* __restrict__ cnt2,
                           int* __restrict__ srcp, float* __restrict__ normp,
                           int* __restrict__ eidx, const int* __restrict__ segB,
                           int* __restrict__ ntiles_p, int* __restrict__ tile_r,
                           int* __restrict__ tile_start, int* __restrict__ tile_len) {
    int b = blockIdx.x, t = threadIdx.x;
    if (b < 2500) {                                 // one edge per thread
        int i = b * 256 + t;
        if (i >= E_EDGES) return;
        int d = dstA[i];
        int key = (d >> 7) * 65 + et[i];
        int p = atomicAdd(&cnt3[key], 1);           // bucket-order position
        srcp[p] = srcA[i];
        normp[p] = norm[i];
        int pos = atomicAdd(&cnt2[d], 1);           // dst-order position
        eidx[pos] = p;                              // dst-order -> bucket-order
    } else {                                        // tile emission (40 blocks)
        int i = (b - 2500) * 256 + t;
        if (i < NKEY_B) {
            int s = segB[i], e = segB[i + 1];
            int len = e - s;
            if (len > 0) {
                int nt = (len + TM - 1) / TM;
                int base = atomicAdd(ntiles_p, nt);
                for (int k = 0; k < nt; ++k) {
                    tile_r[base + k] = i % 65;
                    tile_start[base + k] = s + k * TM;
                    tile_len[base + k] = min(TM, len - k * TM);
                }
            }
        }
    }
}

// ---------------- K4: resid tiles + per-bucket edge GEMM tiles -------------
__global__ __launch_bounds__(256, 3) void k_conv_gemm(
    const int* __restrict__ tile_r, const int* __restrict__ tile_start,
    const int* __restrict__ tile_len, const int* __restrict__ ntiles_p,
    const int* __restrict__ srcp, const float* __restrict__ normp,
    const unsigned short* __restrict__ node_bf,
    const unsigned short* __restrict__ Wt, const unsigned short* __restrict__ Wrest,
    const float* __restrict__ b_res, unsigned short* __restrict__ t_out,
    float* __restrict__ resid) {
    __shared__ unsigned short Blds[128 * 128];      // 32 KB (W, full 128 cols)
    __shared__ unsigned short Alds[64 * 128];       // 16 KB (<=64 gathered rows)
    __shared__ float snorm[64];
    int t = threadIdx.x;
    int w = t >> 6, lane = t & 63;
    int lrow = lane & 15, quad = lane >> 4;

    if (blockIdx.x < NB_RESID) {
        // ---- residual tile: rows row0..row0+63, relu(x@W_res+b) -> resid
        int wr = (w >> 1) * 32, wc = (w & 1) * 64;
        int row0 = blockIdx.x * 64;
        int nrows = min(64, N_NODES - row0);
#pragma unroll
        for (int it = 0; it < 8; ++it) {
            int j = t + 256 * it;
            int o = j >> 4, c = j & 15, cs = c ^ (o & 15);
            async16(Wrest + o * 128 + cs * 8, &Blds[o * 128 + c * 8]);
        }
#pragma unroll
        for (int it = 0; it < 4; ++it) {
            int j = t + 256 * it;
            int p = j >> 4, c = j & 15, cs = c ^ (p & 15);
            if (p < nrows)
                async16(node_bf + (size_t)(row0 + p) * 128 + cs * 8,
                        &Alds[p * 128 + c * 8]);
        }
        __syncthreads();
        f32x4 acc[2][4];
#pragma unroll
        for (int i = 0; i < 2; ++i)
#pragma unroll
            for (int j = 0; j < 4; ++j) acc[i][j] = (f32x4){0.f, 0.f, 0.f, 0.f};
#pragma unroll
        for (int ks = 0; ks < 4; ++ks) {
            int cs = (ks * 4 + quad) ^ lrow;
            bf16x8 af[2], bfr[4];
#pragma unroll
            for (int i = 0; i < 2; ++i)
                af[i] = *reinterpret_cast<const bf16x8*>(&Alds[(wr + i * 16 + lrow) * 128 + cs * 8]);
#pragma unroll
            for (int j = 0; j < 4; ++j)
                bfr[j] = *reinterpret_cast<const bf16x8*>(&Blds[(wc + j * 16 + lrow) * 128 + cs * 8]);
#pragma unroll
            for (int i = 0; i < 2; ++i)
#pragma unroll
                for (int j = 0; j < 4; ++j)
                    acc[i][j] = __builtin_amdgcn_mfma_f32_16x16x32_bf16(af[i], bfr[j], acc[i][j], 0, 0, 0);
        }
        float br0 = b_res[wc + lrow];
        float br1 = b_res[wc + 16 + lrow];
        float br2 = b_res[wc + 32 + lrow];
        float br3 = b_res[wc + 48 + lrow];
#pragma unroll
        for (int i = 0; i < 2; ++i) {
#pragma unroll
            for (int reg = 0; reg < 4; ++reg) {
                int grow = row0 + wr + i * 16 + quad * 4 + reg;
                if (grow < N_NODES) {
                    float4 v;
                    v.x = fmaxf(acc[i][0][reg] + br0, 0.f);
                    v.y = fmaxf(acc[i][1][reg] + br1, 0.f);
                    v.z = fmaxf(acc[i][2][reg] + br2, 0.f);
                    v.w = fmaxf(acc[i][3][reg] + br3, 0.f);
                    *reinterpret_cast<float4*>(resid + (size_t)grow * 128 + wc + lrow * 4) = v;
                }
            }
        }
        return;
    }

    // ---- edge tile: one (dstgrp,rel) bucket chunk, <=64 rows x 128 cols
    int tid = blockIdx.x - NB_RESID;
    if (tid >= *ntiles_p) return;
    int r = tile_r[tid], start = tile_start[tid], len = tile_len[tid];
    const unsigned short* Wr = Wt + (size_t)r * 16384;
#pragma unroll
    for (int it = 0; it < 8; ++it) {               // stage W (XOR on source)
        int j = t + 256 * it;
        int o = j >> 4, c = j & 15, cs = c ^ (o & 15);
        async16(Wr + o * 128 + cs * 8, &Blds[o * 128 + c * 8]);
    }
#pragma unroll
    for (int it = 0; it < 4; ++it) {               // stage A (gathered rows)
        int j = t + 256 * it;
        int p = j >> 4, c = j & 15, cs = c ^ (p & 15);
        if (p < len)
            async16(node_bf + (size_t)srcp[start + p] * 128 + cs * 8,
                    &Alds[p * 128 + c * 8]);
    }
    if (t < TM && t < len) snorm[t] = normp[start + t];
    __syncthreads();

    int wr = w * 16;                                // wave owns 16 rows
    if (wr >= len) return;
    f32x4 acc[8];
#pragma unroll
    for (int j = 0; j < 8; ++j) acc[j] = (f32x4){0.f, 0.f, 0.f, 0.f};
#pragma unroll
    for (int ks = 0; ks < 4; ++ks) {
        int cs = (ks * 4 + quad) ^ lrow;
        bf16x8 af = *reinterpret_cast<const bf16x8*>(&Alds[(wr + lrow) * 128 + cs * 8]);
#pragma unroll
        for (int j = 0; j < 8; ++j) {
            bf16x8 bfr = *reinterpret_cast<const bf16x8*>(&Blds[(j * 16 + lrow) * 128 + cs * 8]);
            acc[j] = __builtin_amdgcn_mfma_f32_16x16x32_bf16(af, bfr, acc[j], 0, 0, 0);
        }
    }

    // epilogue: scale by norm, pack bf16, sequential full-line stores.
    // stored pos p = 64*(j>>2) + lrow*4 + (j&3) <-> true col via unperm().
#pragma unroll
    for (int reg = 0; reg < 4; ++reg) {
        int m = wr + quad * 4 + reg;
        if (m < len) {
            float nm = snorm[m];
            float2 l0 = make_float2(acc[0][reg] * nm, acc[1][reg] * nm);
            float2 l1 = make_float2(acc[2][reg] * nm, acc[3][reg] * nm);
            float2 h0 = make_float2(acc[4][reg] * nm, acc[5][reg] * nm);
            float2 h1 = make_float2(acc[6][reg] * nm, acc[7][reg] * nm);
            __hip_bfloat162 bl0 = __float22bfloat162_rn(l0);
            __hip_bfloat162 bl1 = __float22bfloat162_rn(l1);
            __hip_bfloat162 bh0 = __float22bfloat162_rn(h0);
            __hip_bfloat162 bh1 = __float22bfloat162_rn(h1);
            u32x2 s0, s1;
            s0.x = *reinterpret_cast<unsigned int*>(&bl0);
            s0.y = *reinterpret_cast<unsigned int*>(&bl1);
            s1.x = *reinterpret_cast<unsigned int*>(&bh0);
            s1.y = *reinterpret_cast<unsigned int*>(&bh1);
            unsigned short* rowp = t_out + (size_t)(start + m) * 128;
            *reinterpret_cast<u32x2*>(rowp + lrow * 4)      = s0;
            *reinterpret_cast<u32x2*>(rowp + 64 + lrow * 4) = s1;
        }
    }
}

// ---------------- K5: wave-per-dst reduce via eidx (L2-local gather) -------
__global__ __launch_bounds__(256) void k_reduce_fused(
    const unsigned short* __restrict__ t, const int* __restrict__ seg,
    const int* __restrict__ eidx, const float* __restrict__ resid,
    const float* __restrict__ h_bias, float* __restrict__ h,
    float* __restrict__ colsum, float* __restrict__ colsumsq) {
    __shared__ float cs1[128], cs2[128], sbias[128];
    if (threadIdx.x < 128) {
        cs1[threadIdx.x] = 0.f; cs2[threadIdx.x] = 0.f;
        sbias[threadIdx.x] = h_bias[unperm(threadIdx.x)];
    }
    __syncthreads();
    int w = threadIdx.x >> 6, lane = threadIdx.x & 63;
    int g = lane >> 4, c = lane & 15;
    for (int k = 0; k < 8; ++k) {
        int d = blockIdx.x * 32 + k * 4 + w;
        if (d >= N_NODES) continue;
        int a = seg[d], b = seg[d + 1];
        float s[8];
#pragma unroll
        for (int kk = 0; kk < 8; ++kk) s[kk] = 0.f;
        for (int q = a + g; q < b; q += 32) {
            int er[8];
#pragma unroll
            for (int kk = 0; kk < 8; ++kk) {
                int row = q + 4 * kk;
                er[kk] = eidx[(row < b) ? row : a];
            }
            u32x4 v[8];
#pragma unroll
            for (int kk = 0; kk < 8; ++kk) {
                v[kk] = *reinterpret_cast<const u32x4*>(t + (size_t)er[kk] * 128 + c * 8);
                if (q + 4 * kk >= b) v[kk] = (u32x4){0u, 0u, 0u, 0u};
            }
#pragma unroll
            for (int kk = 0; kk < 8; ++kk)
#pragma unroll
                for (int j = 0; j < 4; ++j) {
                    s[2 * j]     += bf2f_lo(v[kk][j]);
                    s[2 * j + 1] += bf2f_hi(v[kk][j]);
                }
        }
#pragma unroll
        for (int kk = 0; kk < 8; ++kk) {
            s[kk] += __shfl_xor(s[kk], 16);
            s[kk] += __shfl_xor(s[kk], 32);
        }
        if (g == 0) {
            const float* rp = resid + (size_t)d * 128 + c * 8;
            float4 r0 = *reinterpret_cast<const float4*>(rp);
            float4 r1 = *reinterpret_cast<const float4*>(rp + 4);
            float rr[8] = {r0.x, r0.y, r0.z, r0.w, r1.x, r1.y, r1.z, r1.w};
            float v[8];
#pragma unroll
            for (int kk = 0; kk < 8; ++kk)
                v[kk] = fmaxf(s[kk] + sbias[c * 8 + kk], 0.f) + rr[kk];
            float* hp = h + (size_t)d * 128 + c * 8;
            *reinterpret_cast<float4*>(hp)     = make_float4(v[0], v[1], v[2], v[3]);
            *reinterpret_cast<float4*>(hp + 4) = make_float4(v[4], v[5], v[6], v[7]);
#pragma unroll
            for (int kk = 0; kk < 8; ++kk) {
                atomicAdd(&cs1[c * 8 + kk], v[kk]);
                atomicAdd(&cs2[c * 8 + kk], v[kk] * v[kk]);
            }
        }
    }
    __syncthreads();
    if (threadIdx.x < 128) {
        atomicAdd(&colsum[threadIdx.x], cs1[threadIdx.x]);
        atomicAdd(&colsumsq[threadIdx.x], cs2[threadIdx.x]);
    }
}

// ---------------- K6: BN apply + unpermute to natural cols -----------------
__global__ void k_bn(float* __restrict__ h, const float* __restrict__ colsum,
                     const float* __restrict__ colsumsq, const float* __restrict__ gamma,
                     const float* __restrict__ beta) {
    __shared__ float sc[128], sh[128], tile[8][128];
    int t = threadIdx.x;
    if (t < 128) {
        int n = unperm(t);
        float m = colsum[t] * (1.f / N_NODES);
        float var = colsumsq[t] * (1.f / N_NODES) - m * m;
        float s = gamma[n] * rsqrtf(var + 1e-5f);
        sc[t] = s;
        sh[t] = beta[n] - m * s;
    }
    __syncthreads();
    int r = t >> 5;
    int p0 = (t & 31) * 4;
    int n0 = (p0 & 64) + ((p0 >> 2) & 15);
    for (int row0 = blockIdx.x * 8; row0 < N_NODES; row0 += gridDim.x * 8) {
        int row = row0 + r;
        float4 v = make_float4(0.f, 0.f, 0.f, 0.f);
        if (row < N_NODES) v = *reinterpret_cast<float4*>(h + (size_t)row * 128 + p0);
        v.x = v.x * sc[p0] + sh[p0];
        v.y = v.y * sc[p0 + 1] + sh[p0 + 1];
        v.z = v.z * sc[p0 + 2] + sh[p0 + 2];
        v.w = v.w * sc[p0 + 3] + sh[p0 + 3];
        tile[r][n0]      = v.x;
        tile[r][n0 + 16] = v.y;
        tile[r][n0 + 32] = v.z;
        tile[r][n0 + 48] = v.w;
        __syncthreads();
        if (row < N_NODES)
            *reinterpret_cast<float4*>(h + (size_t)row * 128 + p0) =
                *reinterpret_cast<float4*>(&tile[r][p0]);
        __syncthreads();
    }
}

extern "C" void kernel_launch(void* const* d_in, const int* in_sizes, int n_in,
                              void* d_out, int out_size, void* d_ws, size_t ws_size,
                              hipStream_t stream) {
    (void)in_sizes; (void)n_in; (void)out_size; (void)ws_size;
    const float* node_feats = (const float*)d_in[0];
    const int* src    = (const int*)d_in[1];
    const int* dst    = (const int*)d_in[2];
    const int* etype  = (const int*)d_in[3];
    const float* norm = (const float*)d_in[4];
    const float* basis = (const float*)d_in[5];
    const float* comp  = (const float*)d_in[6];
    const float* h_bias = (const float*)d_in[7];
    const float* W_res  = (const float*)d_in[8];
    const float* b_res  = (const float*)d_in[9];
    const float* gamma  = (const float*)d_in[10];
    const float* beta   = (const float*)d_in[11];

    char* ws = (char*)d_ws;
    float* colsum   = (float*)(ws + 0);            // 512
    float* colsumsq = (float*)(ws + 512);          // 512
    int* ntiles_p   = (int*)(ws + 1024);           // 64
    int* gh3        = (int*)(ws + 1088);           // 40820 -> 41908 pad 41920
    int* gh2        = (int*)(ws + 41920);          // 80000 -> 121920 (memset end)
    int* segB       = (int*)(ws + 121920);         // 40824 -> 162744 pad 162752
    int* cnt3       = (int*)(ws + 162752);         // 40820 -> 203572 pad 203584
    int* seg        = (int*)(ws + 203584);         // 80004 -> 283588 pad 283648
    int* cnt2       = (int*)(ws + 283648);         // 80000 -> 363648
    int* tile_r     = (int*)(ws + 363648);         // 81920 -> 445568
    int* tile_start = (int*)(ws + 445568);         // 81920 -> 527488
    int* tile_len   = (int*)(ws + 527488);         // 81920 -> 609408
    unsigned short* Wt      = (unsigned short*)(ws + 609408);    // 2129920 -> 2739328
    unsigned short* Wrest   = (unsigned short*)(ws + 2739328);   // 32768   -> 2772096
    unsigned short* node_bf = (unsigned short*)(ws + 2772096);   // 5120000 -> 7892096
    int* srcp       = (int*)(ws + 7892096);        // 2560000 -> 10452096
    float* normp    = (float*)(ws + 10452096);     // 2560000 -> 13012096
    int* eidx       = (int*)(ws + 13012096);       // 2560000 -> 15572096
    float* resid    = (float*)(ws + 15572096);     // 10240000 -> 25812096
    const long T_BASE = 25812096L;                 // 16B aligned
    float* W32      = (float*)(ws + T_BASE);       // aliased: dead before conv
    unsigned short* t_buf = (unsigned short*)(ws + T_BASE);      // 163.84 MB
    float* hacc = (float*)d_out;

    hipMemsetAsync(ws, 0, 121920, stream);         // colsum..gh2
    k_prep1<<<3332, 256, 0, stream>>>(comp, basis, W32, etype, dst, gh3, gh2,
                                      node_feats, node_bf);
    k_prep3<<<384, 256, 0, stream>>>(gh3, segB, cnt3, gh2, cnt2, seg,
                                     W32, Wt, W_res, Wrest);
    k_scatter2<<<2540, 256, 0, stream>>>(etype, src, dst, norm, cnt3, cnt2,
                                         srcp, normp, eidx, segB, ntiles_p,
                                         tile_r, tile_start, tile_len);
    k_conv_gemm<<<NB_RESID + MAX_TILES, 256, 0, stream>>>(
        tile_r, tile_start, tile_len, ntiles_p, srcp, normp, node_bf,
        Wt, Wrest, b_res, t_buf, resid);
    k_reduce_fused<<<626, 256, 0, stream>>>(t_buf, seg, eidx, resid,
                                            h_bias, hacc, colsum, colsumsq);
    k_bn<<<2500, 256, 0, stream>>>(hacc, colsum, colsumsq, gamma, beta);
}

// Round 7
// 328.079 us; speedup vs baseline: 1.2479x; 1.2479x over previous
//
#include <hip/hip_runtime.h>
#include <hip/hip_bf16.h>

// RGCN layer, MI355X — round 18.
// r17 post-mortem: one-pass scatter wrote 100MB HBM for 7.7MB payload (random
// 4B writes, cross-XCD partial-line flushes) = 116us; 64-row conv tiles
// doubled tile count -> conv ~100us. FIX:
// (1) hierarchical scatter: pass A sorts by dst-grp-128 (157 buckets, r16-
//     style two-phase, 8B/edge), pass B = one block per g128 owns its segment;
//     final positions from a 10400-slot scan ordered (g512, rel, sub) ->
//     all random writes land in single-block-owned L2 windows.
// (2) conv buckets = (g512, rel): 2600 buckets mean 246 edges -> 128-row
//     tiles (~5400, 94% fill) = r16's proven conv shape, sequential writes.
// (3) reduce = r17 body; dst gather window = 4MB (one g512 segment).

#define N_NODES 20000
#define E_EDGES 640000
#define R_REL   65
#define NG5     40                  // ceil(20000/512)
#define NG128   157                 // ceil(20000/128)
#define NSLOT   (NG5 * R_REL * 4)   // 10400
#define NKEY5   (NG5 * R_REL)       // 2600
#define NB_RESID 313
#define MAX_TILES 10240
#define TM      128

typedef __attribute__((ext_vector_type(8))) short bf16x8;
typedef __attribute__((ext_vector_type(4))) float f32x4;
typedef __attribute__((ext_vector_type(4))) unsigned int u32x4;
typedef __attribute__((ext_vector_type(2))) unsigned int u32x2;

__device__ __forceinline__ unsigned short f2bf(float x) {
    union { float f; unsigned int u; } c; c.f = x;
    unsigned int b = c.u + 0x7fffu + ((c.u >> 16) & 1u);   // RTNE
    return (unsigned short)(b >> 16);
}
__device__ __forceinline__ float bf2f_lo(unsigned int u) {
    union { unsigned int u; float f; } c; c.u = u << 16; return c.f;
}
__device__ __forceinline__ float bf2f_hi(unsigned int u) {
    union { unsigned int u; float f; } c; c.u = u & 0xffff0000u; return c.f;
}
__device__ __forceinline__ void async16(const void* g, void* l) {
    __builtin_amdgcn_global_load_lds(
        (const __attribute__((address_space(1))) unsigned int*)g,
        (__attribute__((address_space(3))) unsigned int*)l, 16, 0, 0);
}
__device__ __forceinline__ int unperm(int p) {      // permuted pos -> true col
    return (p & 64) + ((p & 3) << 4) + ((p >> 2) & 15);
}

// ---------------- K1: basis GEMM || slot+dst hist || f32->bf16 cvt ---------
__global__ void k_prep1(const float* __restrict__ comp, const float* __restrict__ basis,
                        float* __restrict__ W32, const int* __restrict__ et,
                        const int* __restrict__ dstA, int* __restrict__ gh3,
                        int* __restrict__ gh2, const float* __restrict__ node_feats,
                        unsigned short* __restrict__ node_bf) {
    __shared__ float lc[16 * 65];
    int b = blockIdx.x, t = threadIdx.x;
    if (b < 320) {                                  // basis GEMM
        int r0 = (b >> 6) * 16;
        int col = (b & 63) * 256 + t;
        for (int j = t; j < 16 * 65; j += 256) {
            int rr = r0 + j / 65;
            lc[j] = (rr < R_REL) ? comp[rr * 65 + (j % 65)] : 0.f;
        }
        __syncthreads();
        float acc[16];
#pragma unroll
        for (int j = 0; j < 16; ++j) acc[j] = 0.f;
        for (int k = 0; k < 65; ++k) {
            float v = basis[k * 16384 + col];
#pragma unroll
            for (int j = 0; j < 16; ++j) acc[j] += lc[j * 65 + k] * v;
        }
#pragma unroll
        for (int j = 0; j < 16; ++j) {
            int rr = r0 + j;
            if (rr < R_REL) W32[rr * 16384 + col] = acc[j];
        }
    } else if (b < 832) {                           // histograms
        for (int i = (b - 320) * 256 + t; i < E_EDGES; i += 512 * 256) {
            int d = dstA[i];
            int slot = ((d >> 9) * 65 + et[i]) * 4 + ((d >> 7) & 3);
            atomicAdd(&gh3[slot], 1);
            atomicAdd(&gh2[d], 1);
        }
    } else {                                        // cvt fp32 -> bf16 (x4)
        int i = (b - 832) * 256 + t;
        if (i < N_NODES * 32) {
            float4 v = reinterpret_cast<const float4*>(node_feats)[i];
            __hip_bfloat162 b0 = __float22bfloat162_rn(make_float2(v.x, v.y));
            __hip_bfloat162 b1 = __float22bfloat162_rn(make_float2(v.z, v.w));
            u32x2 pk;
            pk.x = *reinterpret_cast<unsigned int*>(&b0);
            pk.y = *reinterpret_cast<unsigned int*>(&b1);
            reinterpret_cast<u32x2*>(node_bf)[i] = pk;
        }
    }
}

// ---------------- K2: slot scan || dst scan || W transposes ----------------
__global__ void k_prep3(const int* __restrict__ gh3, int* __restrict__ segAll,
                        const int* __restrict__ gh2, int* __restrict__ seg,
                        const float* __restrict__ W32, unsigned short* __restrict__ Wt,
                        const float* __restrict__ Wresf, unsigned short* __restrict__ Wrest) {
    int b = blockIdx.x, t = threadIdx.x;
    if (b < 41) {                                   // scan 10400 slots
        __shared__ int red[256];
        __shared__ int pref;
        int acc = 0;
        for (int i = t; i < b * 256; i += 256) acc += gh3[i];
        red[t] = acc;
        __syncthreads();
        for (int off = 128; off > 0; off >>= 1) {
            if (t < off) red[t] += red[t + off];
            __syncthreads();
        }
        if (t == 0) pref = red[0];
        __syncthreads();
        int i = b * 256 + t;
        int v = (i < NSLOT) ? gh3[i] : 0;
        red[t] = v;
        __syncthreads();
        for (int off = 1; off < 256; off <<= 1) {
            int x = (t >= off) ? red[t - off] : 0;
            __syncthreads();
            red[t] += x;
            __syncthreads();
        }
        int excl = red[t] - v + pref;
        if (i < NSLOT) {
            segAll[i] = excl;
            if (i == NSLOT - 1) segAll[NSLOT] = excl + v;
        }
    } else if (b < 120) {                           // scan 20000 dsts
        __shared__ int red[256];
        __shared__ int pref;
        int b2 = b - 41;
        int acc = 0;
        for (int i = t; i < b2 * 256; i += 256) acc += gh2[i];
        red[t] = acc;
        __syncthreads();
        for (int off = 128; off > 0; off >>= 1) {
            if (t < off) red[t] += red[t + off];
            __syncthreads();
        }
        if (t == 0) pref = red[0];
        __syncthreads();
        int i = b2 * 256 + t;
        int v = (i < N_NODES) ? gh2[i] : 0;
        red[t] = v;
        __syncthreads();
        for (int off = 1; off < 256; off <<= 1) {
            int x = (t >= off) ? red[t - off] : 0;
            __syncthreads();
            red[t] += x;
            __syncthreads();
        }
        int excl = red[t] - v + pref;
        if (i < N_NODES) {
            seg[i] = excl;
            if (i == N_NODES - 1) seg[N_NODES] = excl + v;
        }
    } else {                                        // transposes (264 blocks)
        __shared__ float tile[64][65];
        int bb = b - 120;
        const float* s; unsigned short* d; int sub;
        if (bb < R_REL * 4) { s = W32 + (size_t)(bb >> 2) * 16384; d = Wt + (size_t)(bb >> 2) * 16384; sub = bb & 3; }
        else { s = Wresf; d = Wrest; sub = bb - R_REL * 4; }
        int ot = (sub >> 1) & 1, itl = sub & 1;
        int tx = t & 63, ty = t >> 6;
        for (int it = 0; it < 16; ++it) {
            int i = ty + it * 4;
            tile[i][tx] = s[(itl * 64 + i) * 128 + ot * 64 + tx];
        }
        __syncthreads();
        for (int it = 0; it < 16; ++it) {
            int o = ty + it * 4;
            d[(ot * 64 + o) * 128 + itl * 64 + tx] = f2bf(tile[tx][o]);
        }
    }
}

// ---------------- K3a: pass A — sort edges by dst-group-128 ----------------
__global__ void k_scatterA(const int* __restrict__ et, const int* __restrict__ srcA,
                           const int* __restrict__ dstA, const float* __restrict__ norm,
                           const int* __restrict__ seg, int* __restrict__ cntA,
                           u32x2* __restrict__ ebuf) {
    __shared__ int lh[NG128], lbase[NG128];
    int c0 = blockIdx.x * 2560;
    int cend = min(c0 + 2560, E_EDGES);
    int t = threadIdx.x;
    for (int i = t; i < NG128; i += 256) lh[i] = 0;
    __syncthreads();
    for (int i = c0 + t; i < cend; i += 256) atomicAdd(&lh[dstA[i] >> 7], 1);
    __syncthreads();
    for (int i = t; i < NG128; i += 256)
        if (lh[i] > 0) lbase[i] = seg[i * 128] + atomicAdd(&cntA[i], lh[i]);
    __syncthreads();
    for (int i = t; i < NG128; i += 256) lh[i] = 0;
    __syncthreads();
    for (int i = c0 + t; i < cend; i += 256) {
        int d = dstA[i];
        int g = d >> 7;
        int p = lbase[g] + atomicAdd(&lh[g], 1);
        u32x2 e;
        e.x = (unsigned)srcA[i] | ((unsigned)(d & 127) << 15) | ((unsigned)et[i] << 22);
        e.y = __float_as_uint(norm[i]);
        ebuf[p] = e;
    }
}

// ---------------- K3b: pass B — within-group bucket sort + tiles -----------
__global__ void k_scatterB(const u32x2* __restrict__ ebuf, const int* __restrict__ seg,
                           const int* __restrict__ segAll, int* __restrict__ srcp,
                           float* __restrict__ normp, int* __restrict__ eidx,
                           int* __restrict__ ntiles_p, int* __restrict__ tile_r,
                           int* __restrict__ tile_start, int* __restrict__ tile_len) {
    int b = blockIdx.x, t = threadIdx.x;
    if (b < NG128) {                                // one block per g128
        __shared__ int base65[R_REL], lcnt[R_REL], sdst[128], ldst[128];
        int g5 = b >> 2, sub = b & 3;
        if (t < R_REL) { base65[t] = segAll[(g5 * 65 + t) * 4 + sub]; lcnt[t] = 0; }
        if (t < 128) {
            int d = b * 128 + t;
            sdst[t] = seg[min(d, N_NODES)];
            ldst[t] = 0;
        }
        __syncthreads();
        int e0 = seg[b * 128];
        int e1 = seg[min((b + 1) * 128, N_NODES)];
        for (int i = e0 + t; i < e1; i += 512) {
            u32x2 e = ebuf[i];
            int src = e.x & 0x7fff;
            int slot = (e.x >> 15) & 127;
            int rel = e.x >> 22;
            int p = base65[rel] + atomicAdd(&lcnt[rel], 1);
            srcp[p] = src;
            normp[p] = __uint_as_float(e.y);
            int pos = sdst[slot] + atomicAdd(&ldst[slot], 1);
            eidx[pos] = p;
        }
    } else {                                        // tile emission (6 blocks)
        int k2 = (b - NG128) * 512 + t;
        if (k2 < NKEY5) {
            int s = segAll[k2 * 4], e = segAll[k2 * 4 + 4];
            int len = e - s;
            if (len > 0) {
                int nt = (len + TM - 1) / TM;
                int base = atomicAdd(ntiles_p, nt);
                for (int k = 0; k < nt; ++k) {
                    tile_r[base + k] = k2 % 65;
                    tile_start[base + k] = s + k * TM;
                    tile_len[base + k] = min(TM, len - k * TM);
                }
            }
        }
    }
}

// ---------------- K4: resid tiles + 128-row edge GEMM tiles ----------------
__global__ __launch_bounds__(256, 2) void k_conv_gemm(
    const int* __restrict__ tile_r, const int* __restrict__ tile_start,
    const int* __restrict__ tile_len, const int* __restrict__ ntiles_p,
    const int* __restrict__ srcp, const float* __restrict__ normp,
    const unsigned short* __restrict__ node_bf,
    const unsigned short* __restrict__ Wt, const unsigned short* __restrict__ Wrest,
    const float* __restrict__ b_res, unsigned short* __restrict__ t_out,
    float* __restrict__ resid) {
    __shared__ unsigned short Alds[128 * 128];      // 32 KB
    __shared__ unsigned short Blds[128 * 128];      // 32 KB
    __shared__ float snorm[128];
    int t = threadIdx.x;
    int w = t >> 6, lane = t & 63;
    int lrow = lane & 15, quad = lane >> 4;

    if (blockIdx.x < NB_RESID) {
        // ---- residual tile: rows row0..row0+63, relu(x@W_res+b) -> resid
        int wr = (w >> 1) * 32, wc = (w & 1) * 64;
        int row0 = blockIdx.x * 64;
        int nrows = min(64, N_NODES - row0);
#pragma unroll
        for (int it = 0; it < 8; ++it) {
            int j = t + 256 * it;
            int o = j >> 4, c = j & 15, cs = c ^ (o & 15);
            async16(Wrest + o * 128 + cs * 8, &Blds[o * 128 + c * 8]);
        }
#pragma unroll
        for (int it = 0; it < 4; ++it) {
            int j = t + 256 * it;
            int p = j >> 4, c = j & 15, cs = c ^ (p & 15);
            if (p < nrows)
                async16(node_bf + (size_t)(row0 + p) * 128 + cs * 8,
                        &Alds[p * 128 + c * 8]);
        }
        __syncthreads();
        f32x4 acc[2][4];
#pragma unroll
        for (int i = 0; i < 2; ++i)
#pragma unroll
            for (int j = 0; j < 4; ++j) acc[i][j] = (f32x4){0.f, 0.f, 0.f, 0.f};
#pragma unroll
        for (int ks = 0; ks < 4; ++ks) {
            int cs = (ks * 4 + quad) ^ lrow;
            bf16x8 af[2], bfr[4];
#pragma unroll
            for (int i = 0; i < 2; ++i)
                af[i] = *reinterpret_cast<const bf16x8*>(&Alds[(wr + i * 16 + lrow) * 128 + cs * 8]);
#pragma unroll
            for (int j = 0; j < 4; ++j)
                bfr[j] = *reinterpret_cast<const bf16x8*>(&Blds[(wc + j * 16 + lrow) * 128 + cs * 8]);
#pragma unroll
            for (int i = 0; i < 2; ++i)
#pragma unroll
                for (int j = 0; j < 4; ++j)
                    acc[i][j] = __builtin_amdgcn_mfma_f32_16x16x32_bf16(af[i], bfr[j], acc[i][j], 0, 0, 0);
        }
        float br0 = b_res[wc + lrow];
        float br1 = b_res[wc + 16 + lrow];
        float br2 = b_res[wc + 32 + lrow];
        float br3 = b_res[wc + 48 + lrow];
#pragma unroll
        for (int i = 0; i < 2; ++i) {
#pragma unroll
            for (int reg = 0; reg < 4; ++reg) {
                int grow = row0 + wr + i * 16 + quad * 4 + reg;
                if (grow < N_NODES) {
                    float4 v;
                    v.x = fmaxf(acc[i][0][reg] + br0, 0.f);
                    v.y = fmaxf(acc[i][1][reg] + br1, 0.f);
                    v.z = fmaxf(acc[i][2][reg] + br2, 0.f);
                    v.w = fmaxf(acc[i][3][reg] + br3, 0.f);
                    *reinterpret_cast<float4*>(resid + (size_t)grow * 128 + wc + lrow * 4) = v;
                }
            }
        }
        return;
    }

    // ---- edge tile: 128 rows x 128 cols, wave w owns rows w*32..+31
    int tid = blockIdx.x - NB_RESID;
    if (tid >= *ntiles_p) return;
    int r = tile_r[tid], start = tile_start[tid], len = tile_len[tid];
    int wr = w * 32;
    const unsigned short* Wr = Wt + (size_t)r * 16384;
#pragma unroll
    for (int it = 0; it < 8; ++it) {               // stage W (XOR on source)
        int j = t + 256 * it;
        int o = j >> 4, c = j & 15, cs = c ^ (o & 15);
        async16(Wr + o * 128 + cs * 8, &Blds[o * 128 + c * 8]);
    }
#pragma unroll
    for (int it = 0; it < 8; ++it) {               // stage A (gathered rows)
        int j = t + 256 * it;
        int p = j >> 4, c = j & 15, cs = c ^ (p & 15);
        if (p < len)
            async16(node_bf + (size_t)srcp[start + p] * 128 + cs * 8,
                    &Alds[p * 128 + c * 8]);
    }
    if (t < TM && t < len) snorm[t] = normp[start + t];
    __syncthreads();

    f32x4 acc[2][8];
#pragma unroll
    for (int i = 0; i < 2; ++i)
#pragma unroll
        for (int j = 0; j < 8; ++j) acc[i][j] = (f32x4){0.f, 0.f, 0.f, 0.f};
#pragma unroll
    for (int ks = 0; ks < 4; ++ks) {
        int cs = (ks * 4 + quad) ^ lrow;
        bf16x8 af[2], bfr[8];
#pragma unroll
        for (int i = 0; i < 2; ++i)
            af[i] = *reinterpret_cast<const bf16x8*>(&Alds[(wr + i * 16 + lrow) * 128 + cs * 8]);
#pragma unroll
        for (int j = 0; j < 8; ++j)
            bfr[j] = *reinterpret_cast<const bf16x8*>(&Blds[(j * 16 + lrow) * 128 + cs * 8]);
#pragma unroll
        for (int i = 0; i < 2; ++i)
#pragma unroll
            for (int j = 0; j < 8; ++j)
                acc[i][j] = __builtin_amdgcn_mfma_f32_16x16x32_bf16(af[i], bfr[j], acc[i][j], 0, 0, 0);
    }

    // epilogue: scale by norm, pack bf16, sequential full-line stores.
#pragma unroll
    for (int i = 0; i < 2; ++i) {
        int m0 = wr + i * 16 + quad * 4;
#pragma unroll
        for (int reg = 0; reg < 4; ++reg) {
            int m = m0 + reg;
            if (m < len) {
                float nm = snorm[m];
                float2 l0 = make_float2(acc[i][0][reg] * nm, acc[i][1][reg] * nm);
                float2 l1 = make_float2(acc[i][2][reg] * nm, acc[i][3][reg] * nm);
                float2 h0 = make_float2(acc[i][4][reg] * nm, acc[i][5][reg] * nm);
                float2 h1 = make_float2(acc[i][6][reg] * nm, acc[i][7][reg] * nm);
                __hip_bfloat162 bl0 = __float22bfloat162_rn(l0);
                __hip_bfloat162 bl1 = __float22bfloat162_rn(l1);
                __hip_bfloat162 bh0 = __float22bfloat162_rn(h0);
                __hip_bfloat162 bh1 = __float22bfloat162_rn(h1);
                u32x2 s0, s1;
                s0.x = *reinterpret_cast<unsigned int*>(&bl0);
                s0.y = *reinterpret_cast<unsigned int*>(&bl1);
                s1.x = *reinterpret_cast<unsigned int*>(&bh0);
                s1.y = *reinterpret_cast<unsigned int*>(&bh1);
                unsigned short* rowp = t_out + (size_t)(start + m) * 128;
                *reinterpret_cast<u32x2*>(rowp + lrow * 4)      = s0;
                *reinterpret_cast<u32x2*>(rowp + 64 + lrow * 4) = s1;
            }
        }
    }
}

// ---------------- K5: wave-per-dst reduce via eidx (L2-local gather) -------
__global__ __launch_bounds__(256) void k_reduce_fused(
    const unsigned short* __restrict__ t, const int* __restrict__ seg,
    const int* __restrict__ eidx, const float* __restrict__ resid,
    const float* __restrict__ h_bias, float* __restrict__ h,
    float* __restrict__ colsum, float* __restrict__ colsumsq) {
    __shared__ float cs1[128], cs2[128], sbias[128];
    if (threadIdx.x < 128) {
        cs1[threadIdx.x] = 0.f; cs2[threadIdx.x] = 0.f;
        sbias[threadIdx.x] = h_bias[unperm(threadIdx.x)];
    }
    __syncthreads();
    int w = threadIdx.x >> 6, lane = threadIdx.x & 63;
    int g = lane >> 4, c = lane & 15;
    for (int k = 0; k < 8; ++k) {
        int d = blockIdx.x * 32 + k * 4 + w;
        if (d >= N_NODES) continue;
        int a = seg[d], b = seg[d + 1];
        float s[8];
#pragma unroll
        for (int kk = 0; kk < 8; ++kk) s[kk] = 0.f;
        for (int q = a + g; q < b; q += 32) {
            int er[8];
#pragma unroll
            for (int kk = 0; kk < 8; ++kk) {
                int row = q + 4 * kk;
                er[kk] = eidx[(row < b) ? row : a];
            }
            u32x4 v[8];
#pragma unroll
            for (int kk = 0; kk < 8; ++kk) {
                v[kk] = *reinterpret_cast<const u32x4*>(t + (size_t)er[kk] * 128 + c * 8);
                if (q + 4 * kk >= b) v[kk] = (u32x4){0u, 0u, 0u, 0u};
            }
#pragma unroll
            for (int kk = 0; kk < 8; ++kk)
#pragma unroll
                for (int j = 0; j < 4; ++j) {
                    s[2 * j]     += bf2f_lo(v[kk][j]);
                    s[2 * j + 1] += bf2f_hi(v[kk][j]);
                }
        }
#pragma unroll
        for (int kk = 0; kk < 8; ++kk) {
            s[kk] += __shfl_xor(s[kk], 16);
            s[kk] += __shfl_xor(s[kk], 32);
        }
        if (g == 0) {
            const float* rp = resid + (size_t)d * 128 + c * 8;
            float4 r0 = *reinterpret_cast<const float4*>(rp);
            float4 r1 = *reinterpret_cast<const float4*>(rp + 4);
            float rr[8] = {r0.x, r0.y, r0.z, r0.w, r1.x, r1.y, r1.z, r1.w};
            float v[8];
#pragma unroll
            for (int kk = 0; kk < 8; ++kk)
                v[kk] = fmaxf(s[kk] + sbias[c * 8 + kk], 0.f) + rr[kk];
            float* hp = h + (size_t)d * 128 + c * 8;
            *reinterpret_cast<float4*>(hp)     = make_float4(v[0], v[1], v[2], v[3]);
            *reinterpret_cast<float4*>(hp + 4) = make_float4(v[4], v[5], v[6], v[7]);
#pragma unroll
            for (int kk = 0; kk < 8; ++kk) {
                atomicAdd(&cs1[c * 8 + kk], v[kk]);
                atomicAdd(&cs2[c * 8 + kk], v[kk] * v[kk]);
            }
        }
    }
    __syncthreads();
    if (threadIdx.x < 128) {
        atomicAdd(&colsum[threadIdx.x], cs1[threadIdx.x]);
        atomicAdd(&colsumsq[threadIdx.x], cs2[threadIdx.x]);
    }
}

// ---------------- K6: BN apply + unpermute to natural cols -----------------
__global__ void k_bn(float* __restrict__ h, const float* __restrict__ colsum,
                     const float* __restrict__ colsumsq, const float* __restrict__ gamma,
                     const float* __restrict__ beta) {
    __shared__ float sc[128], sh[128], tile[8][128];
    int t = threadIdx.x;
    if (t < 128) {
        int n = unperm(t);
        float m = colsum[t] * (1.f / N_NODES);
        float var = colsumsq[t] * (1.f / N_NODES) - m * m;
        float s = gamma[n] * rsqrtf(var + 1e-5f);
        sc[t] = s;
        sh[t] = beta[n] - m * s;
    }
    __syncthreads();
    int r = t >> 5;
    int p0 = (t & 31) * 4;
    int n0 = (p0 & 64) + ((p0 >> 2) & 15);
    for (int row0 = blockIdx.x * 8; row0 < N_NODES; row0 += gridDim.x * 8) {
        int row = row0 + r;
        float4 v = make_float4(0.f, 0.f, 0.f, 0.f);
        if (row < N_NODES) v = *reinterpret_cast<float4*>(h + (size_t)row * 128 + p0);
        v.x = v.x * sc[p0] + sh[p0];
        v.y = v.y * sc[p0 + 1] + sh[p0 + 1];
        v.z = v.z * sc[p0 + 2] + sh[p0 + 2];
        v.w = v.w * sc[p0 + 3] + sh[p0 + 3];
        tile[r][n0]      = v.x;
        tile[r][n0 + 16] = v.y;
        tile[r][n0 + 32] = v.z;
        tile[r][n0 + 48] = v.w;
        __syncthreads();
        if (row < N_NODES)
            *reinterpret_cast<float4*>(h + (size_t)row * 128 + p0) =
                *reinterpret_cast<float4*>(&tile[r][p0]);
        __syncthreads();
    }
}

extern "C" void kernel_launch(void* const* d_in, const int* in_sizes, int n_in,
                              void* d_out, int out_size, void* d_ws, size_t ws_size,
                              hipStream_t stream) {
    (void)in_sizes; (void)n_in; (void)out_size; (void)ws_size;
    const float* node_feats = (const float*)d_in[0];
    const int* src    = (const int*)d_in[1];
    const int* dst    = (const int*)d_in[2];
    const int* etype  = (const int*)d_in[3];
    const float* norm = (const float*)d_in[4];
    const float* basis = (const float*)d_in[5];
    const float* comp  = (const float*)d_in[6];
    const float* h_bias = (const float*)d_in[7];
    const float* W_res  = (const float*)d_in[8];
    const float* b_res  = (const float*)d_in[9];
    const float* gamma  = (const float*)d_in[10];
    const float* beta   = (const float*)d_in[11];

    char* ws = (char*)d_ws;
    float* colsum   = (float*)(ws + 0);            // 512
    float* colsumsq = (float*)(ws + 512);          // 512
    int* ntiles_p   = (int*)(ws + 1024);           // 64
    int* cntA       = (int*)(ws + 1088);           // 628 -> pad 1792
    int* gh3        = (int*)(ws + 1792);           // 41600 -> 43392
    int* gh2        = (int*)(ws + 43392);          // 80000 -> 123392 [memset end]
    int* segAll     = (int*)(ws + 123392);         // 41604 -> 164996 pad 165056
    int* seg        = (int*)(ws + 165056);         // 80004 -> 245060 pad 245120
    int* tile_r     = (int*)(ws + 245120);         // 40960 -> 286080
    int* tile_start = (int*)(ws + 286080);         // 40960 -> 327040
    int* tile_len   = (int*)(ws + 327040);         // 40960 -> 368000
    unsigned short* Wt      = (unsigned short*)(ws + 368000);    // 2129920 -> 2497920
    unsigned short* Wrest   = (unsigned short*)(ws + 2497920);   // 32768   -> 2530688
    unsigned short* node_bf = (unsigned short*)(ws + 2530688);   // 5120000 -> 7650688
    int* srcp       = (int*)(ws + 7650688);        // 2560000 -> 10210688
    float* normp    = (float*)(ws + 10210688);     // 2560000 -> 12770688
    int* eidx       = (int*)(ws + 12770688);       // 2560000 -> 15330688
    u32x2* ebuf     = (u32x2*)(ws + 15330688);     // 5120000 -> 20450688
    float* resid    = (float*)(ws + 20450688);     // 10240000 -> 30690688
    const long T_BASE = 30690688L;                 // 16B aligned
    float* W32      = (float*)(ws + T_BASE);       // aliased: dead before conv
    unsigned short* t_buf = (unsigned short*)(ws + T_BASE);      // 163.84 MB
    float* hacc = (float*)d_out;

    hipMemsetAsync(ws, 0, 123392, stream);         // colsum..gh2
    k_prep1<<<3332, 256, 0, stream>>>(comp, basis, W32, etype, dst, gh3, gh2,
                                      node_feats, node_bf);
    k_prep3<<<384, 256, 0, stream>>>(gh3, segAll, gh2, seg, W32, Wt, W_res, Wrest);
    k_scatterA<<<250, 256, 0, stream>>>(etype, src, dst, norm, seg, cntA, ebuf);
    k_scatterB<<<163, 512, 0, stream>>>(ebuf, seg, segAll, srcp, normp, eidx,
                                        ntiles_p, tile_r, tile_start, tile_len);
    k_conv_gemm<<<NB_RESID + MAX_TILES, 256, 0, stream>>>(
        tile_r, tile_start, tile_len, ntiles_p, srcp, normp, node_bf,
        Wt, Wrest, b_res, t_buf, resid);
    k_reduce_fused<<<626, 256, 0, stream>>>(t_buf, seg, eidx, resid,
                                            h_bias, hacc, colsum, colsumsq);
    k_bn<<<2500, 256, 0, stream>>>(hacc, colsum, colsumsq, gamma, beta);
}

// Round 8
// 291.753 us; speedup vs baseline: 1.4033x; 1.1245x over previous
//
#include <hip/hip_runtime.h>
#include <hip/hip_bf16.h>

// RGCN layer, MI355X — round 19.
// r18 post-mortem: 328us but conv(85)+reduce(<84) leaves ~160us hidden in
// prep/scatter. prep1's 1.28M random cross-XCD global atomics (dst+slot
// hists) = the r17-scatter2 pathology. Conv FETCH 112MB vs ~15 ideal: t_buf
// write stream thrashes L3, evicting node_bf/Wt (7MB hot set, 4MB L2/XCD).
// FIX: (1) prep1 hist -> 64 blocks x LDS packed-16bit hists + coalesced
// merge; (2) conv t_buf stores non-temporal (sequential full lines; keeps
// L3 for node_bf/Wt; reduce FETCH will show the cost side); (3) scatterB
// 1024 threads. Everything else = r18.

#define N_NODES 20000
#define E_EDGES 640000
#define R_REL   65
#define NG5     40                  // ceil(20000/512)
#define NG128   157                 // ceil(20000/128)
#define NSLOT   (NG5 * R_REL * 4)   // 10400
#define NKEY5   (NG5 * R_REL)       // 2600
#define NB_RESID 313
#define MAX_TILES 10240
#define TM      128

typedef __attribute__((ext_vector_type(8))) short bf16x8;
typedef __attribute__((ext_vector_type(4))) float f32x4;
typedef __attribute__((ext_vector_type(4))) unsigned int u32x4;
typedef __attribute__((ext_vector_type(2))) unsigned int u32x2;

__device__ __forceinline__ unsigned short f2bf(float x) {
    union { float f; unsigned int u; } c; c.f = x;
    unsigned int b = c.u + 0x7fffu + ((c.u >> 16) & 1u);   // RTNE
    return (unsigned short)(b >> 16);
}
__device__ __forceinline__ float bf2f_lo(unsigned int u) {
    union { unsigned int u; float f; } c; c.u = u << 16; return c.f;
}
__device__ __forceinline__ float bf2f_hi(unsigned int u) {
    union { unsigned int u; float f; } c; c.u = u & 0xffff0000u; return c.f;
}
__device__ __forceinline__ void async16(const void* g, void* l) {
    __builtin_amdgcn_global_load_lds(
        (const __attribute__((address_space(1))) unsigned int*)g,
        (__attribute__((address_space(3))) unsigned int*)l, 16, 0, 0);
}
__device__ __forceinline__ int unperm(int p) {      // permuted pos -> true col
    return (p & 64) + ((p & 3) << 4) + ((p >> 2) & 15);
}

// ---------------- K1: basis GEMM || LDS hists || f32->bf16 cvt -------------
__global__ void k_prep1(const float* __restrict__ comp, const float* __restrict__ basis,
                        float* __restrict__ W32, const int* __restrict__ et,
                        const int* __restrict__ dstA, int* __restrict__ gh3,
                        int* __restrict__ gh2, const float* __restrict__ node_feats,
                        unsigned short* __restrict__ node_bf) {
    __shared__ int shbuf[15200];                    // 60.8 KB, aliased per-section
    int b = blockIdx.x, t = threadIdx.x;
    if (b < 320) {                                  // basis GEMM
        float* lc = (float*)shbuf;                  // 16*65 floats
        int r0 = (b >> 6) * 16;
        int col = (b & 63) * 256 + t;
        for (int j = t; j < 16 * 65; j += 256) {
            int rr = r0 + j / 65;
            lc[j] = (rr < R_REL) ? comp[rr * 65 + (j % 65)] : 0.f;
        }
        __syncthreads();
        float acc[16];
#pragma unroll
        for (int j = 0; j < 16; ++j) acc[j] = 0.f;
        for (int k = 0; k < 65; ++k) {
            float v = basis[k * 16384 + col];
#pragma unroll
            for (int j = 0; j < 16; ++j) acc[j] += lc[j * 65 + k] * v;
        }
#pragma unroll
        for (int j = 0; j < 16; ++j) {
            int rr = r0 + j;
            if (rr < R_REL) W32[rr * 16384 + col] = acc[j];
        }
    } else if (b < 384) {                           // LDS-packed histograms
        int* pk2 = shbuf;                           // 10000 ints (20000 dst ctrs)
        int* pk3 = shbuf + 10000;                   // 5200 ints (10400 slot ctrs)
        for (int i = t; i < 15200; i += 256) shbuf[i] = 0;
        __syncthreads();
        for (int i = (b - 320) * 256 + t; i < E_EDGES; i += 64 * 256) {
            int d = dstA[i];
            int slot = ((d >> 9) * 65 + et[i]) * 4 + ((d >> 7) & 3);
            atomicAdd(&pk2[d >> 1], (int)(1u << ((d & 1) << 4)));
            atomicAdd(&pk3[slot >> 1], (int)(1u << ((slot & 1) << 4)));
        }
        __syncthreads();
        for (int i = t; i < 10000; i += 256) {      // coalesced merge
            unsigned v = (unsigned)pk2[i];
            if (v & 0xffffu) atomicAdd(&gh2[2 * i], (int)(v & 0xffffu));
            if (v >> 16)     atomicAdd(&gh2[2 * i + 1], (int)(v >> 16));
        }
        for (int i = t; i < 5200; i += 256) {
            unsigned v = (unsigned)pk3[i];
            if (v & 0xffffu) atomicAdd(&gh3[2 * i], (int)(v & 0xffffu));
            if (v >> 16)     atomicAdd(&gh3[2 * i + 1], (int)(v >> 16));
        }
    } else {                                        // cvt fp32 -> bf16 (x4)
        int i = (b - 384) * 256 + t;
        if (i < N_NODES * 32) {
            float4 v = reinterpret_cast<const float4*>(node_feats)[i];
            __hip_bfloat162 b0 = __float22bfloat162_rn(make_float2(v.x, v.y));
            __hip_bfloat162 b1 = __float22bfloat162_rn(make_float2(v.z, v.w));
            u32x2 pk;
            pk.x = *reinterpret_cast<unsigned int*>(&b0);
            pk.y = *reinterpret_cast<unsigned int*>(&b1);
            reinterpret_cast<u32x2*>(node_bf)[i] = pk;
        }
    }
}

// ---------------- K2: slot scan || dst scan || W transposes ----------------
__global__ void k_prep3(const int* __restrict__ gh3, int* __restrict__ segAll,
                        const int* __restrict__ gh2, int* __restrict__ seg,
                        const float* __restrict__ W32, unsigned short* __restrict__ Wt,
                        const float* __restrict__ Wresf, unsigned short* __restrict__ Wrest) {
    int b = blockIdx.x, t = threadIdx.x;
    if (b < 41) {                                   // scan 10400 slots
        __shared__ int red[256];
        __shared__ int pref;
        int acc = 0;
        for (int i = t; i < b * 256; i += 256) acc += gh3[i];
        red[t] = acc;
        __syncthreads();
        for (int off = 128; off > 0; off >>= 1) {
            if (t < off) red[t] += red[t + off];
            __syncthreads();
        }
        if (t == 0) pref = red[0];
        __syncthreads();
        int i = b * 256 + t;
        int v = (i < NSLOT) ? gh3[i] : 0;
        red[t] = v;
        __syncthreads();
        for (int off = 1; off < 256; off <<= 1) {
            int x = (t >= off) ? red[t - off] : 0;
            __syncthreads();
            red[t] += x;
            __syncthreads();
        }
        int excl = red[t] - v + pref;
        if (i < NSLOT) {
            segAll[i] = excl;
            if (i == NSLOT - 1) segAll[NSLOT] = excl + v;
        }
    } else if (b < 120) {                           // scan 20000 dsts
        __shared__ int red[256];
        __shared__ int pref;
        int b2 = b - 41;
        int acc = 0;
        for (int i = t; i < b2 * 256; i += 256) acc += gh2[i];
        red[t] = acc;
        __syncthreads();
        for (int off = 128; off > 0; off >>= 1) {
            if (t < off) red[t] += red[t + off];
            __syncthreads();
        }
        if (t == 0) pref = red[0];
        __syncthreads();
        int i = b2 * 256 + t;
        int v = (i < N_NODES) ? gh2[i] : 0;
        red[t] = v;
        __syncthreads();
        for (int off = 1; off < 256; off <<= 1) {
            int x = (t >= off) ? red[t - off] : 0;
            __syncthreads();
            red[t] += x;
            __syncthreads();
        }
        int excl = red[t] - v + pref;
        if (i < N_NODES) {
            seg[i] = excl;
            if (i == N_NODES - 1) seg[N_NODES] = excl + v;
        }
    } else {                                        // transposes (264 blocks)
        __shared__ float tile[64][65];
        int bb = b - 120;
        const float* s; unsigned short* d; int sub;
        if (bb < R_REL * 4) { s = W32 + (size_t)(bb >> 2) * 16384; d = Wt + (size_t)(bb >> 2) * 16384; sub = bb & 3; }
        else { s = Wresf; d = Wrest; sub = bb - R_REL * 4; }
        int ot = (sub >> 1) & 1, itl = sub & 1;
        int tx = t & 63, ty = t >> 6;
        for (int it = 0; it < 16; ++it) {
            int i = ty + it * 4;
            tile[i][tx] = s[(itl * 64 + i) * 128 + ot * 64 + tx];
        }
        __syncthreads();
        for (int it = 0; it < 16; ++it) {
            int o = ty + it * 4;
            d[(ot * 64 + o) * 128 + itl * 64 + tx] = f2bf(tile[tx][o]);
        }
    }
}

// ---------------- K3a: pass A — sort edges by dst-group-128 ----------------
__global__ void k_scatterA(const int* __restrict__ et, const int* __restrict__ srcA,
                           const int* __restrict__ dstA, const float* __restrict__ norm,
                           const int* __restrict__ seg, int* __restrict__ cntA,
                           u32x2* __restrict__ ebuf) {
    __shared__ int lh[NG128], lbase[NG128];
    int c0 = blockIdx.x * 2560;
    int cend = min(c0 + 2560, E_EDGES);
    int t = threadIdx.x;
    for (int i = t; i < NG128; i += 256) lh[i] = 0;
    __syncthreads();
    for (int i = c0 + t; i < cend; i += 256) atomicAdd(&lh[dstA[i] >> 7], 1);
    __syncthreads();
    for (int i = t; i < NG128; i += 256)
        if (lh[i] > 0) lbase[i] = seg[i * 128] + atomicAdd(&cntA[i], lh[i]);
    __syncthreads();
    for (int i = t; i < NG128; i += 256) lh[i] = 0;
    __syncthreads();
    for (int i = c0 + t; i < cend; i += 256) {
        int d = dstA[i];
        int g = d >> 7;
        int p = lbase[g] + atomicAdd(&lh[g], 1);
        u32x2 e;
        e.x = (unsigned)srcA[i] | ((unsigned)(d & 127) << 15) | ((unsigned)et[i] << 22);
        e.y = __float_as_uint(norm[i]);
        ebuf[p] = e;
    }
}

// ---------------- K3b: pass B — within-group bucket sort + tiles -----------
__global__ void k_scatterB(const u32x2* __restrict__ ebuf, const int* __restrict__ seg,
                           const int* __restrict__ segAll, int* __restrict__ srcp,
                           float* __restrict__ normp, int* __restrict__ eidx,
                           int* __restrict__ ntiles_p, int* __restrict__ tile_r,
                           int* __restrict__ tile_start, int* __restrict__ tile_len) {
    int b = blockIdx.x, t = threadIdx.x;
    if (b < NG128) {                                // one block per g128
        __shared__ int base65[R_REL], lcnt[R_REL], sdst[128], ldst[128];
        int g5 = b >> 2, sub = b & 3;
        if (t < R_REL) { base65[t] = segAll[(g5 * 65 + t) * 4 + sub]; lcnt[t] = 0; }
        if (t < 128) {
            int d = b * 128 + t;
            sdst[t] = seg[min(d, N_NODES)];
            ldst[t] = 0;
        }
        __syncthreads();
        int e0 = seg[b * 128];
        int e1 = seg[min((b + 1) * 128, N_NODES)];
        for (int i = e0 + t; i < e1; i += 1024) {
            u32x2 e = ebuf[i];
            int src = e.x & 0x7fff;
            int slot = (e.x >> 15) & 127;
            int rel = e.x >> 22;
            int p = base65[rel] + atomicAdd(&lcnt[rel], 1);
            srcp[p] = src;
            normp[p] = __uint_as_float(e.y);
            int pos = sdst[slot] + atomicAdd(&ldst[slot], 1);
            eidx[pos] = p;
        }
    } else {                                        // tile emission (3 blocks)
        int k2 = (b - NG128) * 1024 + t;
        if (k2 < NKEY5) {
            int s = segAll[k2 * 4], e = segAll[k2 * 4 + 4];
            int len = e - s;
            if (len > 0) {
                int nt = (len + TM - 1) / TM;
                int base = atomicAdd(ntiles_p, nt);
                for (int k = 0; k < nt; ++k) {
                    tile_r[base + k] = k2 % 65;
                    tile_start[base + k] = s + k * TM;
                    tile_len[base + k] = min(TM, len - k * TM);
                }
            }
        }
    }
}

// ---------------- K4: resid tiles + 128-row edge GEMM tiles ----------------
__global__ __launch_bounds__(256, 2) void k_conv_gemm(
    const int* __restrict__ tile_r, const int* __restrict__ tile_start,
    const int* __restrict__ tile_len, const int* __restrict__ ntiles_p,
    const int* __restrict__ srcp, const float* __restrict__ normp,
    const unsigned short* __restrict__ node_bf,
    const unsigned short* __restrict__ Wt, const unsigned short* __restrict__ Wrest,
    const float* __restrict__ b_res, unsigned short* __restrict__ t_out,
    float* __restrict__ resid) {
    __shared__ unsigned short Alds[128 * 128];      // 32 KB
    __shared__ unsigned short Blds[128 * 128];      // 32 KB
    __shared__ float snorm[128];
    int t = threadIdx.x;
    int w = t >> 6, lane = t & 63;
    int lrow = lane & 15, quad = lane >> 4;

    if (blockIdx.x < NB_RESID) {
        // ---- residual tile: rows row0..row0+63, relu(x@W_res+b) -> resid
        int wr = (w >> 1) * 32, wc = (w & 1) * 64;
        int row0 = blockIdx.x * 64;
        int nrows = min(64, N_NODES - row0);
#pragma unroll
        for (int it = 0; it < 8; ++it) {
            int j = t + 256 * it;
            int o = j >> 4, c = j & 15, cs = c ^ (o & 15);
            async16(Wrest + o * 128 + cs * 8, &Blds[o * 128 + c * 8]);
        }
#pragma unroll
        for (int it = 0; it < 4; ++it) {
            int j = t + 256 * it;
            int p = j >> 4, c = j & 15, cs = c ^ (p & 15);
            if (p < nrows)
                async16(node_bf + (size_t)(row0 + p) * 128 + cs * 8,
                        &Alds[p * 128 + c * 8]);
        }
        __syncthreads();
        f32x4 acc[2][4];
#pragma unroll
        for (int i = 0; i < 2; ++i)
#pragma unroll
            for (int j = 0; j < 4; ++j) acc[i][j] = (f32x4){0.f, 0.f, 0.f, 0.f};
#pragma unroll
        for (int ks = 0; ks < 4; ++ks) {
            int cs = (ks * 4 + quad) ^ lrow;
            bf16x8 af[2], bfr[4];
#pragma unroll
            for (int i = 0; i < 2; ++i)
                af[i] = *reinterpret_cast<const bf16x8*>(&Alds[(wr + i * 16 + lrow) * 128 + cs * 8]);
#pragma unroll
            for (int j = 0; j < 4; ++j)
                bfr[j] = *reinterpret_cast<const bf16x8*>(&Blds[(wc + j * 16 + lrow) * 128 + cs * 8]);
#pragma unroll
            for (int i = 0; i < 2; ++i)
#pragma unroll
                for (int j = 0; j < 4; ++j)
                    acc[i][j] = __builtin_amdgcn_mfma_f32_16x16x32_bf16(af[i], bfr[j], acc[i][j], 0, 0, 0);
        }
        float br0 = b_res[wc + lrow];
        float br1 = b_res[wc + 16 + lrow];
        float br2 = b_res[wc + 32 + lrow];
        float br3 = b_res[wc + 48 + lrow];
#pragma unroll
        for (int i = 0; i < 2; ++i) {
#pragma unroll
            for (int reg = 0; reg < 4; ++reg) {
                int grow = row0 + wr + i * 16 + quad * 4 + reg;
                if (grow < N_NODES) {
                    float4 v;
                    v.x = fmaxf(acc[i][0][reg] + br0, 0.f);
                    v.y = fmaxf(acc[i][1][reg] + br1, 0.f);
                    v.z = fmaxf(acc[i][2][reg] + br2, 0.f);
                    v.w = fmaxf(acc[i][3][reg] + br3, 0.f);
                    *reinterpret_cast<float4*>(resid + (size_t)grow * 128 + wc + lrow * 4) = v;
                }
            }
        }
        return;
    }

    // ---- edge tile: 128 rows x 128 cols, wave w owns rows w*32..+31
    int tid = blockIdx.x - NB_RESID;
    if (tid >= *ntiles_p) return;
    int r = tile_r[tid], start = tile_start[tid], len = tile_len[tid];
    int wr = w * 32;
    const unsigned short* Wr = Wt + (size_t)r * 16384;
#pragma unroll
    for (int it = 0; it < 8; ++it) {               // stage W (XOR on source)
        int j = t + 256 * it;
        int o = j >> 4, c = j & 15, cs = c ^ (o & 15);
        async16(Wr + o * 128 + cs * 8, &Blds[o * 128 + c * 8]);
    }
#pragma unroll
    for (int it = 0; it < 8; ++it) {               // stage A (gathered rows)
        int j = t + 256 * it;
        int p = j >> 4, c = j & 15, cs = c ^ (p & 15);
        if (p < len)
            async16(node_bf + (size_t)srcp[start + p] * 128 + cs * 8,
                    &Alds[p * 128 + c * 8]);
    }
    if (t < TM && t < len) snorm[t] = normp[start + t];
    __syncthreads();

    f32x4 acc[2][8];
#pragma unroll
    for (int i = 0; i < 2; ++i)
#pragma unroll
        for (int j = 0; j < 8; ++j) acc[i][j] = (f32x4){0.f, 0.f, 0.f, 0.f};
#pragma unroll
    for (int ks = 0; ks < 4; ++ks) {
        int cs = (ks * 4 + quad) ^ lrow;
        bf16x8 af[2], bfr[8];
#pragma unroll
        for (int i = 0; i < 2; ++i)
            af[i] = *reinterpret_cast<const bf16x8*>(&Alds[(wr + i * 16 + lrow) * 128 + cs * 8]);
#pragma unroll
        for (int j = 0; j < 8; ++j)
            bfr[j] = *reinterpret_cast<const bf16x8*>(&Blds[(j * 16 + lrow) * 128 + cs * 8]);
#pragma unroll
        for (int i = 0; i < 2; ++i)
#pragma unroll
            for (int j = 0; j < 8; ++j)
                acc[i][j] = __builtin_amdgcn_mfma_f32_16x16x32_bf16(af[i], bfr[j], acc[i][j], 0, 0, 0);
    }

    // epilogue: scale by norm, pack bf16, NON-TEMPORAL sequential stores
    // (keep the 164MB stream out of L3 so node_bf/Wt stay resident).
#pragma unroll
    for (int i = 0; i < 2; ++i) {
        int m0 = wr + i * 16 + quad * 4;
#pragma unroll
        for (int reg = 0; reg < 4; ++reg) {
            int m = m0 + reg;
            if (m < len) {
                float nm = snorm[m];
                float2 l0 = make_float2(acc[i][0][reg] * nm, acc[i][1][reg] * nm);
                float2 l1 = make_float2(acc[i][2][reg] * nm, acc[i][3][reg] * nm);
                float2 h0 = make_float2(acc[i][4][reg] * nm, acc[i][5][reg] * nm);
                float2 h1 = make_float2(acc[i][6][reg] * nm, acc[i][7][reg] * nm);
                __hip_bfloat162 bl0 = __float22bfloat162_rn(l0);
                __hip_bfloat162 bl1 = __float22bfloat162_rn(l1);
                __hip_bfloat162 bh0 = __float22bfloat162_rn(h0);
                __hip_bfloat162 bh1 = __float22bfloat162_rn(h1);
                u32x2 s0, s1;
                s0.x = *reinterpret_cast<unsigned int*>(&bl0);
                s0.y = *reinterpret_cast<unsigned int*>(&bl1);
                s1.x = *reinterpret_cast<unsigned int*>(&bh0);
                s1.y = *reinterpret_cast<unsigned int*>(&bh1);
                unsigned short* rowp = t_out + (size_t)(start + m) * 128;
                __builtin_nontemporal_store(s0, reinterpret_cast<u32x2*>(rowp + lrow * 4));
                __builtin_nontemporal_store(s1, reinterpret_cast<u32x2*>(rowp + 64 + lrow * 4));
            }
        }
    }
}

// ---------------- K5: wave-per-dst reduce via eidx (L2-local gather) -------
__global__ __launch_bounds__(256) void k_reduce_fused(
    const unsigned short* __restrict__ t, const int* __restrict__ seg,
    const int* __restrict__ eidx, const float* __restrict__ resid,
    const float* __restrict__ h_bias, float* __restrict__ h,
    float* __restrict__ colsum, float* __restrict__ colsumsq) {
    __shared__ float cs1[128], cs2[128], sbias[128];
    if (threadIdx.x < 128) {
        cs1[threadIdx.x] = 0.f; cs2[threadIdx.x] = 0.f;
        sbias[threadIdx.x] = h_bias[unperm(threadIdx.x)];
    }
    __syncthreads();
    int w = threadIdx.x >> 6, lane = threadIdx.x & 63;
    int g = lane >> 4, c = lane & 15;
    for (int k = 0; k < 8; ++k) {
        int d = blockIdx.x * 32 + k * 4 + w;
        if (d >= N_NODES) continue;
        int a = seg[d], b = seg[d + 1];
        float s[8];
#pragma unroll
        for (int kk = 0; kk < 8; ++kk) s[kk] = 0.f;
        for (int q = a + g; q < b; q += 32) {
            int er[8];
#pragma unroll
            for (int kk = 0; kk < 8; ++kk) {
                int row = q + 4 * kk;
                er[kk] = eidx[(row < b) ? row : a];
            }
            u32x4 v[8];
#pragma unroll
            for (int kk = 0; kk < 8; ++kk) {
                v[kk] = *reinterpret_cast<const u32x4*>(t + (size_t)er[kk] * 128 + c * 8);
                if (q + 4 * kk >= b) v[kk] = (u32x4){0u, 0u, 0u, 0u};
            }
#pragma unroll
            for (int kk = 0; kk < 8; ++kk)
#pragma unroll
                for (int j = 0; j < 4; ++j) {
                    s[2 * j]     += bf2f_lo(v[kk][j]);
                    s[2 * j + 1] += bf2f_hi(v[kk][j]);
                }
        }
#pragma unroll
        for (int kk = 0; kk < 8; ++kk) {
            s[kk] += __shfl_xor(s[kk], 16);
            s[kk] += __shfl_xor(s[kk], 32);
        }
        if (g == 0) {
            const float* rp = resid + (size_t)d * 128 + c * 8;
            float4 r0 = *reinterpret_cast<const float4*>(rp);
            float4 r1 = *reinterpret_cast<const float4*>(rp + 4);
            float rr[8] = {r0.x, r0.y, r0.z, r0.w, r1.x, r1.y, r1.z, r1.w};
            float v[8];
#pragma unroll
            for (int kk = 0; kk < 8; ++kk)
                v[kk] = fmaxf(s[kk] + sbias[c * 8 + kk], 0.f) + rr[kk];
            float* hp = h + (size_t)d * 128 + c * 8;
            *reinterpret_cast<float4*>(hp)     = make_float4(v[0], v[1], v[2], v[3]);
            *reinterpret_cast<float4*>(hp + 4) = make_float4(v[4], v[5], v[6], v[7]);
#pragma unroll
            for (int kk = 0; kk < 8; ++kk) {
                atomicAdd(&cs1[c * 8 + kk], v[kk]);
                atomicAdd(&cs2[c * 8 + kk], v[kk] * v[kk]);
            }
        }
    }
    __syncthreads();
    if (threadIdx.x < 128) {
        atomicAdd(&colsum[threadIdx.x], cs1[threadIdx.x]);
        atomicAdd(&colsumsq[threadIdx.x], cs2[threadIdx.x]);
    }
}

// ---------------- K6: BN apply + unpermute to natural cols -----------------
__global__ void k_bn(float* __restrict__ h, const float* __restrict__ colsum,
                     const float* __restrict__ colsumsq, const float* __restrict__ gamma,
                     const float* __restrict__ beta) {
    __shared__ float sc[128], sh[128], tile[8][128];
    int t = threadIdx.x;
    if (t < 128) {
        int n = unperm(t);
        float m = colsum[t] * (1.f / N_NODES);
        float var = colsumsq[t] * (1.f / N_NODES) - m * m;
        float s = gamma[n] * rsqrtf(var + 1e-5f);
        sc[t] = s;
        sh[t] = beta[n] - m * s;
    }
    __syncthreads();
    int r = t >> 5;
    int p0 = (t & 31) * 4;
    int n0 = (p0 & 64) + ((p0 >> 2) & 15);
    for (int row0 = blockIdx.x * 8; row0 < N_NODES; row0 += gridDim.x * 8) {
        int row = row0 + r;
        float4 v = make_float4(0.f, 0.f, 0.f, 0.f);
        if (row < N_NODES) v = *reinterpret_cast<float4*>(h + (size_t)row * 128 + p0);
        v.x = v.x * sc[p0] + sh[p0];
        v.y = v.y * sc[p0 + 1] + sh[p0 + 1];
        v.z = v.z * sc[p0 + 2] + sh[p0 + 2];
        v.w = v.w * sc[p0 + 3] + sh[p0 + 3];
        tile[r][n0]      = v.x;
        tile[r][n0 + 16] = v.y;
        tile[r][n0 + 32] = v.z;
        tile[r][n0 + 48] = v.w;
        __syncthreads();
        if (row < N_NODES)
            *reinterpret_cast<float4*>(h + (size_t)row * 128 + p0) =
                *reinterpret_cast<float4*>(&tile[r][p0]);
        __syncthreads();
    }
}

extern "C" void kernel_launch(void* const* d_in, const int* in_sizes, int n_in,
                              void* d_out, int out_size, void* d_ws, size_t ws_size,
                              hipStream_t stream) {
    (void)in_sizes; (void)n_in; (void)out_size; (void)ws_size;
    const float* node_feats = (const float*)d_in[0];
    const int* src    = (const int*)d_in[1];
    const int* dst    = (const int*)d_in[2];
    const int* etype  = (const int*)d_in[3];
    const float* norm = (const float*)d_in[4];
    const float* basis = (const float*)d_in[5];
    const float* comp  = (const float*)d_in[6];
    const float* h_bias = (const float*)d_in[7];
    const float* W_res  = (const float*)d_in[8];
    const float* b_res  = (const float*)d_in[9];
    const float* gamma  = (const float*)d_in[10];
    const float* beta   = (const float*)d_in[11];

    char* ws = (char*)d_ws;
    float* colsum   = (float*)(ws + 0);            // 512
    float* colsumsq = (float*)(ws + 512);          // 512
    int* ntiles_p   = (int*)(ws + 1024);           // 64
    int* cntA       = (int*)(ws + 1088);           // 628 -> pad 1792
    int* gh3        = (int*)(ws + 1792);           // 41600 -> 43392
    int* gh2        = (int*)(ws + 43392);          // 80000 -> 123392 [memset end]
    int* segAll     = (int*)(ws + 123392);         // 41604 -> 164996 pad 165056
    int* seg        = (int*)(ws + 165056);         // 80004 -> 245060 pad 245120
    int* tile_r     = (int*)(ws + 245120);         // 40960 -> 286080
    int* tile_start = (int*)(ws + 286080);         // 40960 -> 327040
    int* tile_len   = (int*)(ws + 327040);         // 40960 -> 368000
    unsigned short* Wt      = (unsigned short*)(ws + 368000);    // 2129920 -> 2497920
    unsigned short* Wrest   = (unsigned short*)(ws + 2497920);   // 32768   -> 2530688
    unsigned short* node_bf = (unsigned short*)(ws + 2530688);   // 5120000 -> 7650688
    int* srcp       = (int*)(ws + 7650688);        // 2560000 -> 10210688
    float* normp    = (float*)(ws + 10210688);     // 2560000 -> 12770688
    int* eidx       = (int*)(ws + 12770688);       // 2560000 -> 15330688
    u32x2* ebuf     = (u32x2*)(ws + 15330688);     // 5120000 -> 20450688
    float* resid    = (float*)(ws + 20450688);     // 10240000 -> 30690688
    const long T_BASE = 30690688L;                 // 16B aligned
    float* W32      = (float*)(ws + T_BASE);       // aliased: dead before conv
    unsigned short* t_buf = (unsigned short*)(ws + T_BASE);      // 163.84 MB
    float* hacc = (float*)d_out;

    hipMemsetAsync(ws, 0, 123392, stream);         // colsum..gh2
    k_prep1<<<2884, 256, 0, stream>>>(comp, basis, W32, etype, dst, gh3, gh2,
                                      node_feats, node_bf);
    k_prep3<<<384, 256, 0, stream>>>(gh3, segAll, gh2, seg, W32, Wt, W_res, Wrest);
    k_scatterA<<<250, 256, 0, stream>>>(etype, src, dst, norm, seg, cntA, ebuf);
    k_scatterB<<<160, 1024, 0, stream>>>(ebuf, seg, segAll, srcp, normp, eidx,
                                         ntiles_p, tile_r, tile_start, tile_len);
    k_conv_gemm<<<NB_RESID + MAX_TILES, 256, 0, stream>>>(
        tile_r, tile_start, tile_len, ntiles_p, srcp, normp, node_bf,
        Wt, Wrest, b_res, t_buf, resid);
    k_reduce_fused<<<626, 256, 0, stream>>>(t_buf, seg, eidx, resid,
                                            h_bias, hacc, colsum, colsumsq);
    k_bn<<<2500, 256, 0, stream>>>(hacc, colsum, colsumsq, gamma, beta);
}